// Round 10
// baseline (282.791 us; speedup 1.0000x reference)
//
#include <hip/hip_runtime.h>
#include <stdint.h>

// Problem dims
#define BB   512
#define NNN  64
#define HHH  256
#define BN_  32768   // B*N
#define H2_  512
#define H3_  768

typedef unsigned short u16;
typedef unsigned int   u32;
typedef __attribute__((ext_vector_type(8)))  short bf16x8;   // 8 bf16 in 4 VGPRs
typedef __attribute__((ext_vector_type(4)))  float f32x4;
typedef __attribute__((ext_vector_type(16))) float f32x16;

__device__ __forceinline__ u16 f2bf(float f) {
  union { float f; u32 u; } x; x.f = f;
  return (u16)((x.u + 0x7fffu + ((x.u >> 16) & 1u)) >> 16);  // RNE
}
__device__ __forceinline__ float bf2f(u16 v) {
  union { u32 u; float f; } x; x.u = ((u32)v) << 16; return x.f;
}
__device__ __forceinline__ void async16(const void* g, void* l) {
  __builtin_amdgcn_global_load_lds(
      (const __attribute__((address_space(1))) u32*)(uintptr_t)g,
      (__attribute__((address_space(3))) u32*)(uintptr_t)l, 16, 0, 0);
}
__device__ __forceinline__ float sigmoidf_(float x) { return 1.0f / (1.0f + __expf(-x)); }
__device__ __forceinline__ float tanhf_(float x)    { return 2.0f / (1.0f + __expf(-2.0f * x)) - 1.0f; }

// ---------------------------------------------------------------- K0: f32 weights -> bf16 wcat
// wcat layout (elems): [W_in 65536 | W_out 65536 | w_ih 393216 | w_hh 196608]
__global__ __launch_bounds__(256) void k_convert(const float* __restrict__ W_in,
                                                 const float* __restrict__ W_out,
                                                 const float* __restrict__ w_ih,
                                                 const float* __restrict__ w_hh,
                                                 u16* __restrict__ wcat) {
  int i = blockIdx.x * 256 + threadIdx.x;
  const float* src; int off;
  if (i < 65536)       { src = W_in;  off = i; }
  else if (i < 131072) { src = W_out; off = i - 65536; }
  else if (i < 524288) { src = w_ih;  off = i - 131072; }
  else                 { src = w_hh;  off = i - 524288; }
  wcat[i] = f2bf(src[off]);
}

// ---------------------------------------------------------------- K1: gather + L2 norm
__global__ __launch_bounds__(256) void k_gather_norm(const int* __restrict__ idx,
                                                     const float* __restrict__ emb,
                                                     u16* __restrict__ h) {
  int row  = blockIdx.x * 4 + (threadIdx.x >> 6);
  int lane = threadIdx.x & 63;
  int e = idx[row];
  float4 v = *(const float4*)(emb + (size_t)e * HHH + lane * 4);
  float s = v.x * v.x + v.y * v.y + v.z * v.z + v.w * v.w;
  for (int off = 32; off; off >>= 1) s += __shfl_xor(s, off, 64);
  float sc = 1.0f / (sqrtf(s) + 1e-12f);
  ushort4 o;
  o.x = f2bf(v.x * sc); o.y = f2bf(v.y * sc); o.z = f2bf(v.z * sc); o.w = f2bf(v.w * sc);
  *(ushort4*)(h + (size_t)row * HHH + lane * 4) = o;
}

// ---------------------------------------------------------------- K2: HioT = wcat @ h^T (+bias)
// A-op = h node rows (M), B-op = wcat channel rows (N) -> C[node][ch]; epilogue transposes
// through LDS so HBM stores are 16B/lane coalesced. HioT[b][c][node64].
__global__ __launch_bounds__(256) void k_hio(const u16* __restrict__ h,
                                             const u16* __restrict__ wcat,
                                             const float* __restrict__ b_in,
                                             const float* __restrict__ b_out,
                                             u16* __restrict__ HioT) {
  __shared__ __align__(16) char smem[34816];         // phase1: Ws 16K | Hs 16K ; phase2: Tt [128][136] u16
  u16* Ws = (u16*)smem;
  u16* Hs = Ws + 8192;
  u16* Tt = (u16*)smem;
  int c0 = blockIdx.y * 128;
  int n0 = blockIdx.x * 128;
  int t = threadIdx.x, w = t >> 6, lane = t & 63;
  int wm = w >> 1, wn = w & 1;    // wm: node half, wn: channel half
  int rsub = lane >> 3, kofs = ((lane & 7) ^ rsub) << 3;
  const u16* wbase = wcat + (size_t)c0 * 256;
  f32x4 acc[4][4];   // [node-tile][ch-tile]
  for (int a = 0; a < 4; ++a) for (int b = 0; b < 4; ++b) acc[a][b] = (f32x4)0.0f;

  for (int kt = 0; kt < 4; ++kt) {
    int k0 = kt * 64;
    for (int i = 0; i < 4; ++i) {
      int r = 32 * w + 8 * i;
      async16(wbase + (size_t)(r + rsub) * 256 + k0 + kofs, &Ws[r * 64]);
      async16(h + (size_t)(n0 + r + rsub) * 256 + k0 + kofs, &Hs[r * 64]);
    }
    __syncthreads();
    for (int ks = 0; ks < 2; ++ks) {
      int c = ks * 4 + (lane >> 4);
      bf16x8 af[4], bf[4];
      for (int mt = 0; mt < 4; ++mt) {
        int r = 64 * wm + 16 * mt + (lane & 15);
        af[mt] = *(const bf16x8*)(Hs + r * 64 + ((c ^ (r & 7)) << 3));
      }
      for (int nt = 0; nt < 4; ++nt) {
        int r = 64 * wn + 16 * nt + (lane & 15);
        bf[nt] = *(const bf16x8*)(Ws + r * 64 + ((c ^ (r & 7)) << 3));
      }
      for (int mt = 0; mt < 4; ++mt)
        for (int nt = 0; nt < 4; ++nt)
          acc[mt][nt] = __builtin_amdgcn_mfma_f32_16x16x32_bf16(af[mt], bf[nt], acc[mt][nt], 0, 0, 0);
    }
    __syncthreads();
  }
  // epilogue: bias + pack 4 consecutive nodes per b64 into Tt[ch][node(pad 136)]
  for (int nt = 0; nt < 4; ++nt) {
    int chl = 64 * wn + 16 * nt + (lane & 15);
    int cg = c0 + chl;
    float bv = (cg < 256) ? b_in[cg] : b_out[cg - 256];
    for (int mt = 0; mt < 4; ++mt) {
      int nb = 64 * wm + 16 * mt + (lane >> 4) * 4;
      u32 lo = (u32)f2bf(acc[mt][nt][0] + bv) | ((u32)f2bf(acc[mt][nt][1] + bv) << 16);
      u32 hi = (u32)f2bf(acc[mt][nt][2] + bv) | ((u32)f2bf(acc[mt][nt][3] + bv) << 16);
      *(uint2*)(Tt + chl * 136 + nb) = make_uint2(lo, hi);
    }
  }
  __syncthreads();
  // coalesced store: 8 iters, 16B per thread
  for (int it = 0; it < 8; ++it) {
    int id = it * 256 + t;                 // [128 ch][2 nblk][8 chunk]
    int ch = id >> 4, nb = (id >> 3) & 1, c8 = id & 7;
    uint4 v = *(const uint4*)(Tt + ch * 136 + nb * 64 + c8 * 8);
    *(uint4*)(HioT + (size_t)((n0 >> 6) + nb) * 32768 + (size_t)(c0 + ch) * 64 + c8 * 8) = v;
  }
}

// ---------------------------------------------------------------- K3: per-batch adjacency matmul
// co passes split across blockIdx.y (1024 blocks); passes share only read-only As and write
// disjoint inp halves.
__global__ __launch_bounds__(256) void k_amul(const float* __restrict__ Ag,
                                              const u16* __restrict__ HioT,
                                              const float* __restrict__ b_iah,
                                              const float* __restrict__ b_oah,
                                              u16* __restrict__ inp) {
  __shared__ __align__(16) u16 As[64 * 136];   // A[b]: 64 x 128 bf16, pad->136
  __shared__ __align__(16) u16 Hs[256 * 64];   // phase: HioT half (swz) ; then Tt2 [64 node][256 ch] xor16B
  int b = blockIdx.x;
  int co = blockIdx.y;
  int t = threadIdx.x, w = t >> 6, lane = t & 63;
  int rsub = lane >> 3, kofs = ((lane & 7) ^ rsub) << 3;
  {
    int r = t >> 2, q = t & 3;
    const float4* src = (const float4*)(Ag + (size_t)b * 8192 + r * 128 + q * 32);
    u16* dst = As + r * 136 + q * 32;
    for (int j = 0; j < 8; ++j) {
      float4 v = src[j];
      ushort4 o;
      o.x = f2bf(v.x); o.y = f2bf(v.y); o.z = f2bf(v.z); o.w = f2bf(v.w);
      *(ushort4*)(dst + j * 4) = o;
    }
  }
  __syncthreads();
  for (int i = 0; i < 2; ++i) {
    int rb = 64 * w + 32 * i;
    for (int s = 0; s < 4; ++s)
      async16(HioT + (size_t)b * 32768 + (size_t)(co * 256 + rb + 8 * s + rsub) * 64 + kofs,
              &Hs[(rb + 8 * s) * 64]);
  }
  __syncthreads();
  f32x4 acc[4][4];   // [ch-tile][node-tile]
  for (int a = 0; a < 4; ++a) for (int c = 0; c < 4; ++c) acc[a][c] = (f32x4)0.0f;
  for (int ks = 0; ks < 2; ++ks) {
    int c = ks * 4 + (lane >> 4);            // node-chunk
    int kk = co * 64 + ks * 32 + (lane >> 4) * 8;
    bf16x8 af[4], bf[4];
    for (int mt = 0; mt < 4; ++mt) {
      int r = 64 * w + 16 * mt + (lane & 15);   // ch row (within 256-half)
      af[mt] = *(const bf16x8*)(Hs + r * 64 + ((c ^ (r & 7)) << 3));
    }
    for (int nt = 0; nt < 4; ++nt) {
      int n = 16 * nt + (lane & 15);
      bf[nt] = *(const bf16x8*)(As + n * 136 + kk);
    }
    for (int mt = 0; mt < 4; ++mt)
      for (int nt = 0; nt < 4; ++nt)
        acc[mt][nt] = __builtin_amdgcn_mfma_f32_16x16x32_bf16(af[mt], bf[nt], acc[mt][nt], 0, 0, 0);
  }
  __syncthreads();   // done reading Hs; reuse as Tt2
  const float* bias = (co == 0) ? b_iah : b_oah;
  u16* Tt2 = Hs;     // [64 node][256 ch], 16B-chunk xor swizzle by (node&7)
  for (int mt = 0; mt < 4; ++mt) {
    int chb = 64 * w + 16 * mt + (lane >> 4) * 4;
    float b0 = bias[chb], b1 = bias[chb + 1], b2 = bias[chb + 2], b3 = bias[chb + 3];
    for (int nt = 0; nt < 4; ++nt) {
      int node = 16 * nt + (lane & 15);
      u32 lo = (u32)f2bf(acc[mt][nt][0] + b0) | ((u32)f2bf(acc[mt][nt][1] + b1) << 16);
      u32 hi = (u32)f2bf(acc[mt][nt][2] + b2) | ((u32)f2bf(acc[mt][nt][3] + b3) << 16);
      int byte = node * 512 + (((chb >> 3) ^ (node & 7)) << 4) + (chb & 7) * 2;
      *(uint2*)((char*)Tt2 + byte) = make_uint2(lo, hi);
    }
  }
  __syncthreads();
  for (int it = 0; it < 8; ++it) {
    int id = it * 256 + t;                 // [64 node][32 chunk16B]
    int node = id >> 5, c = id & 31;
    uint4 v = *(const uint4*)((char*)Tt2 + node * 512 + ((c ^ (node & 7)) << 4));
    *(uint4*)(inp + ((size_t)b * 64 + node) * 512 + co * 256 + c * 8) = v;
  }
}

// ---------------------------------------------------------------- K4: fused gate GEMM + GRU (32x32x16)
// v10 = v9 (64-col j-tile, acc=64, VGPR 68 -> big headroom) + T3 2-phase LDS double-buffer:
//   per kt: STAGE(kt+1, buf^1) -> sched_barrier -> compute(kt, buf) -> __syncthreads().
//   The end-of-iteration __syncthreads drains vmcnt(0) AFTER compute, so stage(kt+1) had the
//   whole compute phase to land (round-2's version drained BEFORE compute = zero overlap).
//   13 barriers total (was 24), stage latency hidden. LDS 2x32KB = 64KB -> 2 blocks/CU.
//   Staging pointers recomputed per kt (round-7-proven register-safe; WRITE_SIZE is the
//   spill canary and must stay 32768 KB).
// acc: a0=i_r+h_r, a1=i_i+h_i, a2=i_n (kt 0..7), a3=h_n (kt 8..11).
__global__ __launch_bounds__(256, 2) void k_gates(const u16* __restrict__ inp,
                                                  const u16* __restrict__ h,
                                                  const u16* __restrict__ wcat,
                                                  const float* __restrict__ b_ih,
                                                  const float* __restrict__ b_hh,
                                                  float* __restrict__ out) {
  __shared__ __align__(16) u16 Xs[2][4096];    // 16 KB: X tile [64 rows][64 K] per buf
  __shared__ __align__(16) u16 Ws[2][12288];   // 48 KB: 3 slabs x [64 rows][64 K] per buf
  const u16* wih_b = wcat + 131072;   // [768,512]
  const u16* whh_b = wcat + 524288;   // [768,256]
  int m0 = blockIdx.x * 64;
  int j0 = blockIdx.y * 64;           // 0..3 -> cols j0..j0+63
  int t = threadIdx.x, w = t >> 6, lane = t & 63;
  int wm = w >> 1, wn = w & 1;        // wm: row half (32), wn: col strip (32)
  int rsub8 = lane >> 3, kofs8 = ((lane & 7) ^ rsub8) << 3;
  f32x16 acc[4];
  for (int g = 0; g < 4; ++g) acc[g] = (f32x16)0.0f;

  // ---- STAGE(kt, b): 2 X calls + 6 W calls per thread; pointers die before compute ----
#define STAGE_KT(kt_, b_)                                                           \
  {                                                                                 \
    bool lo_ = ((kt_) < 8);                                                         \
    int k0_ = lo_ ? (kt_) * 64 : ((kt_) - 8) * 64;                                  \
    const u16* wb_ = lo_ ? wih_b : whh_b;                                           \
    int wp_ = lo_ ? 512 : 256;                                                      \
    const u16* xb_ = lo_ ? (inp + (size_t)m0 * 512 + (kt_) * 64)                    \
                         : (h   + (size_t)m0 * 256 + ((kt_) - 8) * 64);             \
    int xp_ = lo_ ? 512 : 256;                                                      \
    for (int i_ = 0; i_ < 2; ++i_) {                                                \
      int og_ = i_ * 4 + w;                                                         \
      async16(xb_ + (size_t)(og_ * 8 + rsub8) * xp_ + kofs8, &Xs[b_][og_ * 8 * 64]);\
    }                                                                               \
    for (int i_ = 0; i_ < 6; ++i_) {                                                \
      int og_ = i_ * 4 + w;                                                         \
      int s_ = og_ >> 3, seg_ = og_ & 7;                                            \
      int jrow_ = s_ * 256 + j0 + seg_ * 8 + rsub8;                                 \
      async16(wb_ + (size_t)jrow_ * wp_ + k0_ + kofs8,                              \
              &Ws[b_][s_ * 4096 + seg_ * 8 * 64]);                                  \
    }                                                                               \
  }

  // prologue: stage kt=0 into buf0; drain (exposed once)
  STAGE_KT(0, 0);
  __syncthreads();

  int rA = 32 * wm + (lane & 31);
  int rB = 32 * wn + (lane & 31);
#pragma unroll 1
  for (int kt = 0; kt < 12; ++kt) {
    int buf = kt & 1;
    if (kt < 11) STAGE_KT(kt + 1, buf ^ 1);
    __builtin_amdgcn_sched_barrier(0);   // pin: stage issues stay above the ds_reads
    bool lo = (kt < 8);
    const u16* Xb = &Xs[buf][0];
    const u16* Wb = &Ws[buf][0];
    for (int ks = 0; ks < 4; ++ks) {
      int c = ks * 2 + (lane >> 5);
      bf16x8 af = *(const bf16x8*)(Xb + rA * 64 + ((c ^ (rA & 7)) << 3));
      int aB = rB * 64 + ((c ^ (rB & 7)) << 3);
      bf16x8 b0 = *(const bf16x8*)(Wb + aB);
      bf16x8 b1 = *(const bf16x8*)(Wb + 4096 + aB);
      bf16x8 b2 = *(const bf16x8*)(Wb + 8192 + aB);
      acc[0] = __builtin_amdgcn_mfma_f32_32x32x16_bf16(af, b0, acc[0], 0, 0, 0);
      acc[1] = __builtin_amdgcn_mfma_f32_32x32x16_bf16(af, b1, acc[1], 0, 0, 0);
      if (lo) acc[2] = __builtin_amdgcn_mfma_f32_32x32x16_bf16(af, b2, acc[2], 0, 0, 0);
      else    acc[3] = __builtin_amdgcn_mfma_f32_32x32x16_bf16(af, b2, acc[3], 0, 0, 0);
    }
    __syncthreads();   // drains stage(kt+1) (landed during compute) + syncs buf reads
  }
#undef STAGE_KT

  // epilogue: stage h tile [64 rows][j0..j0+64) into Hh = Xs[0] (8KB, linear)
  u16* Hh = &Xs[0][0];
  {
    for (int i = 0; i < 2; ++i) {
      int og = i * 4 + w;                               // 0..7 -> rows og*8..+7
      async16(h + (size_t)(m0 + og * 8 + rsub8) * 256 + j0 + (lane & 7) * 8,
              &Hh[og * 8 * 64]);
    }
  }
  __syncthreads();
  // gates in-register; hv from Hh (linear [64][64]); hy -> F f32[64][64] (aliases Ws[0])
  float* F = (float*)&Ws[0][0];       // 16 KB of the 24 KB slab
  int jl = 32 * wn + (lane & 31);
  int j = j0 + jl;
  float brs = b_ih[j] + b_hh[j];
  float bis = b_ih[256 + j] + b_hh[256 + j];
  float bin = b_ih[512 + j];
  float bhn = b_hh[512 + j];
#pragma unroll
  for (int e = 0; e < 16; ++e) {
    int row = (e & 3) + 8 * (e >> 2) + 4 * (lane >> 5);
    int mloc = 32 * wm + row;
    float r  = sigmoidf_(acc[0][e] + brs);
    float ig = sigmoidf_(acc[1][e] + bis);
    float hn = acc[3][e] + bhn;
    float ng = tanhf_(acc[2][e] + bin + r * hn);
    float hv = bf2f(Hh[mloc * 64 + jl]);
    F[mloc * 64 + jl] = ng + ig * (hv - ng);
  }
  __syncthreads();
  for (int it = 0; it < 8; ++it) {
    int id = it * 256 + t;            // [64 m][32 j-pairs]
    int mloc = id >> 5, jp = (id & 31) * 2;
    float2 v = *(const float2*)(F + mloc * 64 + jp);
    *(float2*)(out + (size_t)(m0 + mloc) * 256 + j0 + jp) = v;
  }
}

extern "C" void kernel_launch(void* const* d_in, const int* in_sizes, int n_in,
                              void* d_out, int out_size, void* d_ws, size_t ws_size,
                              hipStream_t stream) {
  (void)in_sizes; (void)n_in; (void)out_size; (void)ws_size;
  const int*   inputs = (const int*)d_in[0];
  const float* A      = (const float*)d_in[1];
  const float* emb    = (const float*)d_in[2];
  const float* W_in   = (const float*)d_in[3];
  const float* b_in   = (const float*)d_in[4];
  const float* W_out  = (const float*)d_in[5];
  const float* b_out  = (const float*)d_in[6];
  const float* w_ih   = (const float*)d_in[7];
  const float* b_ih   = (const float*)d_in[8];
  const float* w_hh   = (const float*)d_in[9];
  const float* b_hh   = (const float*)d_in[10];
  const float* b_iah  = (const float*)d_in[11];
  const float* b_oah  = (const float*)d_in[12];
  float* out = (float*)d_out;

  u16* h    = (u16*)d_ws;                 // BN*256 bf16 = 16.8 MB
  u16* HioT = h + (size_t)BN_ * HHH;      // 33.6 MB
  u16* inp  = HioT + (size_t)BN_ * H2_;   // 33.6 MB
  u16* wcat = inp + (size_t)BN_ * H2_;    // 1.44 MB

  k_convert<<<2816, 256, 0, stream>>>(W_in, W_out, w_ih, w_hh, wcat);
  k_gather_norm<<<BN_ / 4, 256, 0, stream>>>(inputs, emb, h);
  k_hio<<<dim3(BN_ / 128, 4), 256, 0, stream>>>(h, wcat, b_in, b_out, HioT);
  k_amul<<<dim3(BB, 2), 256, 0, stream>>>(A, HioT, b_iah, b_oah, inp);
  k_gates<<<dim3(BN_ / 64, 4), 256, 0, stream>>>(inp, h, wcat, b_ih, b_hh, out);
}

// Round 11
// 276.523 us; speedup vs baseline: 1.0227x; 1.0227x over previous
//
#include <hip/hip_runtime.h>
#include <stdint.h>

// Problem dims
#define BB   512
#define NNN  64
#define HHH  256
#define BN_  32768   // B*N
#define H2_  512
#define H3_  768

typedef unsigned short u16;
typedef unsigned int   u32;
typedef __attribute__((ext_vector_type(8)))  short bf16x8;   // 8 bf16 in 4 VGPRs
typedef __attribute__((ext_vector_type(4)))  float f32x4;
typedef __attribute__((ext_vector_type(16))) float f32x16;

__device__ __forceinline__ u16 f2bf(float f) {
  union { float f; u32 u; } x; x.f = f;
  return (u16)((x.u + 0x7fffu + ((x.u >> 16) & 1u)) >> 16);  // RNE
}
__device__ __forceinline__ float bf2f(u16 v) {
  union { u32 u; float f; } x; x.u = ((u32)v) << 16; return x.f;
}
__device__ __forceinline__ void async16(const void* g, void* l) {
  __builtin_amdgcn_global_load_lds(
      (const __attribute__((address_space(1))) u32*)(uintptr_t)g,
      (__attribute__((address_space(3))) u32*)(uintptr_t)l, 16, 0, 0);
}
__device__ __forceinline__ float sigmoidf_(float x) { return 1.0f / (1.0f + __expf(-x)); }
__device__ __forceinline__ float tanhf_(float x)    { return 2.0f / (1.0f + __expf(-2.0f * x)) - 1.0f; }

// ---------------------------------------------------------------- K0: f32 weights -> bf16 wcat
// wcat layout (elems): [W_in 65536 | W_out 65536 | w_ih 393216 | w_hh 196608]
__global__ __launch_bounds__(256) void k_convert(const float* __restrict__ W_in,
                                                 const float* __restrict__ W_out,
                                                 const float* __restrict__ w_ih,
                                                 const float* __restrict__ w_hh,
                                                 u16* __restrict__ wcat) {
  int i = blockIdx.x * 256 + threadIdx.x;
  const float* src; int off;
  if (i < 65536)       { src = W_in;  off = i; }
  else if (i < 131072) { src = W_out; off = i - 65536; }
  else if (i < 524288) { src = w_ih;  off = i - 131072; }
  else                 { src = w_hh;  off = i - 524288; }
  wcat[i] = f2bf(src[off]);
}

// ---------------------------------------------------------------- K1: gather + L2 norm
__global__ __launch_bounds__(256) void k_gather_norm(const int* __restrict__ idx,
                                                     const float* __restrict__ emb,
                                                     u16* __restrict__ h) {
  int row  = blockIdx.x * 4 + (threadIdx.x >> 6);
  int lane = threadIdx.x & 63;
  int e = idx[row];
  float4 v = *(const float4*)(emb + (size_t)e * HHH + lane * 4);
  float s = v.x * v.x + v.y * v.y + v.z * v.z + v.w * v.w;
  for (int off = 32; off; off >>= 1) s += __shfl_xor(s, off, 64);
  float sc = 1.0f / (sqrtf(s) + 1e-12f);
  ushort4 o;
  o.x = f2bf(v.x * sc); o.y = f2bf(v.y * sc); o.z = f2bf(v.z * sc); o.w = f2bf(v.w * sc);
  *(ushort4*)(h + (size_t)row * HHH + lane * 4) = o;
}

// ---------------------------------------------------------------- K2: HioT = wcat @ h^T (+bias)
// A-op = h node rows (M), B-op = wcat channel rows (N) -> C[node][ch]; epilogue transposes
// through LDS so HBM stores are 16B/lane coalesced. HioT[b][c][node64].
__global__ __launch_bounds__(256) void k_hio(const u16* __restrict__ h,
                                             const u16* __restrict__ wcat,
                                             const float* __restrict__ b_in,
                                             const float* __restrict__ b_out,
                                             u16* __restrict__ HioT) {
  __shared__ __align__(16) char smem[34816];         // phase1: Ws 16K | Hs 16K ; phase2: Tt [128][136] u16
  u16* Ws = (u16*)smem;
  u16* Hs = Ws + 8192;
  u16* Tt = (u16*)smem;
  int c0 = blockIdx.y * 128;
  int n0 = blockIdx.x * 128;
  int t = threadIdx.x, w = t >> 6, lane = t & 63;
  int wm = w >> 1, wn = w & 1;    // wm: node half, wn: channel half
  int rsub = lane >> 3, kofs = ((lane & 7) ^ rsub) << 3;
  const u16* wbase = wcat + (size_t)c0 * 256;
  f32x4 acc[4][4];   // [node-tile][ch-tile]
  for (int a = 0; a < 4; ++a) for (int b = 0; b < 4; ++b) acc[a][b] = (f32x4)0.0f;

  for (int kt = 0; kt < 4; ++kt) {
    int k0 = kt * 64;
    for (int i = 0; i < 4; ++i) {
      int r = 32 * w + 8 * i;
      async16(wbase + (size_t)(r + rsub) * 256 + k0 + kofs, &Ws[r * 64]);
      async16(h + (size_t)(n0 + r + rsub) * 256 + k0 + kofs, &Hs[r * 64]);
    }
    __syncthreads();
    for (int ks = 0; ks < 2; ++ks) {
      int c = ks * 4 + (lane >> 4);
      bf16x8 af[4], bf[4];
      for (int mt = 0; mt < 4; ++mt) {
        int r = 64 * wm + 16 * mt + (lane & 15);
        af[mt] = *(const bf16x8*)(Hs + r * 64 + ((c ^ (r & 7)) << 3));
      }
      for (int nt = 0; nt < 4; ++nt) {
        int r = 64 * wn + 16 * nt + (lane & 15);
        bf[nt] = *(const bf16x8*)(Ws + r * 64 + ((c ^ (r & 7)) << 3));
      }
      for (int mt = 0; mt < 4; ++mt)
        for (int nt = 0; nt < 4; ++nt)
          acc[mt][nt] = __builtin_amdgcn_mfma_f32_16x16x32_bf16(af[mt], bf[nt], acc[mt][nt], 0, 0, 0);
    }
    __syncthreads();
  }
  // epilogue: bias + pack 4 consecutive nodes per b64 into Tt[ch][node(pad 136)]
  for (int nt = 0; nt < 4; ++nt) {
    int chl = 64 * wn + 16 * nt + (lane & 15);
    int cg = c0 + chl;
    float bv = (cg < 256) ? b_in[cg] : b_out[cg - 256];
    for (int mt = 0; mt < 4; ++mt) {
      int nb = 64 * wm + 16 * mt + (lane >> 4) * 4;
      u32 lo = (u32)f2bf(acc[mt][nt][0] + bv) | ((u32)f2bf(acc[mt][nt][1] + bv) << 16);
      u32 hi = (u32)f2bf(acc[mt][nt][2] + bv) | ((u32)f2bf(acc[mt][nt][3] + bv) << 16);
      *(uint2*)(Tt + chl * 136 + nb) = make_uint2(lo, hi);
    }
  }
  __syncthreads();
  // coalesced store: 8 iters, 16B per thread
  for (int it = 0; it < 8; ++it) {
    int id = it * 256 + t;                 // [128 ch][2 nblk][8 chunk]
    int ch = id >> 4, nb = (id >> 3) & 1, c8 = id & 7;
    uint4 v = *(const uint4*)(Tt + ch * 136 + nb * 64 + c8 * 8);
    *(uint4*)(HioT + (size_t)((n0 >> 6) + nb) * 32768 + (size_t)(c0 + ch) * 64 + c8 * 8) = v;
  }
}

// ---------------------------------------------------------------- K3: per-batch adjacency matmul
// co passes split across blockIdx.y (1024 blocks); passes share only read-only As and write
// disjoint inp halves.
__global__ __launch_bounds__(256) void k_amul(const float* __restrict__ Ag,
                                              const u16* __restrict__ HioT,
                                              const float* __restrict__ b_iah,
                                              const float* __restrict__ b_oah,
                                              u16* __restrict__ inp) {
  __shared__ __align__(16) u16 As[64 * 136];   // A[b]: 64 x 128 bf16, pad->136
  __shared__ __align__(16) u16 Hs[256 * 64];   // phase: HioT half (swz) ; then Tt2 [64 node][256 ch] xor16B
  int b = blockIdx.x;
  int co = blockIdx.y;
  int t = threadIdx.x, w = t >> 6, lane = t & 63;
  int rsub = lane >> 3, kofs = ((lane & 7) ^ rsub) << 3;
  {
    int r = t >> 2, q = t & 3;
    const float4* src = (const float4*)(Ag + (size_t)b * 8192 + r * 128 + q * 32);
    u16* dst = As + r * 136 + q * 32;
    for (int j = 0; j < 8; ++j) {
      float4 v = src[j];
      ushort4 o;
      o.x = f2bf(v.x); o.y = f2bf(v.y); o.z = f2bf(v.z); o.w = f2bf(v.w);
      *(ushort4*)(dst + j * 4) = o;
    }
  }
  __syncthreads();
  for (int i = 0; i < 2; ++i) {
    int rb = 64 * w + 32 * i;
    for (int s = 0; s < 4; ++s)
      async16(HioT + (size_t)b * 32768 + (size_t)(co * 256 + rb + 8 * s + rsub) * 64 + kofs,
              &Hs[(rb + 8 * s) * 64]);
  }
  __syncthreads();
  f32x4 acc[4][4];   // [ch-tile][node-tile]
  for (int a = 0; a < 4; ++a) for (int c = 0; c < 4; ++c) acc[a][c] = (f32x4)0.0f;
  for (int ks = 0; ks < 2; ++ks) {
    int c = ks * 4 + (lane >> 4);            // node-chunk
    int kk = co * 64 + ks * 32 + (lane >> 4) * 8;
    bf16x8 af[4], bf[4];
    for (int mt = 0; mt < 4; ++mt) {
      int r = 64 * w + 16 * mt + (lane & 15);   // ch row (within 256-half)
      af[mt] = *(const bf16x8*)(Hs + r * 64 + ((c ^ (r & 7)) << 3));
    }
    for (int nt = 0; nt < 4; ++nt) {
      int n = 16 * nt + (lane & 15);
      bf[nt] = *(const bf16x8*)(As + n * 136 + kk);
    }
    for (int mt = 0; mt < 4; ++mt)
      for (int nt = 0; nt < 4; ++nt)
        acc[mt][nt] = __builtin_amdgcn_mfma_f32_16x16x32_bf16(af[mt], bf[nt], acc[mt][nt], 0, 0, 0);
  }
  __syncthreads();   // done reading Hs; reuse as Tt2
  const float* bias = (co == 0) ? b_iah : b_oah;
  u16* Tt2 = Hs;     // [64 node][256 ch], 16B-chunk xor swizzle by (node&7)
  for (int mt = 0; mt < 4; ++mt) {
    int chb = 64 * w + 16 * mt + (lane >> 4) * 4;
    float b0 = bias[chb], b1 = bias[chb + 1], b2 = bias[chb + 2], b3 = bias[chb + 3];
    for (int nt = 0; nt < 4; ++nt) {
      int node = 16 * nt + (lane & 15);
      u32 lo = (u32)f2bf(acc[mt][nt][0] + b0) | ((u32)f2bf(acc[mt][nt][1] + b1) << 16);
      u32 hi = (u32)f2bf(acc[mt][nt][2] + b2) | ((u32)f2bf(acc[mt][nt][3] + b3) << 16);
      int byte = node * 512 + (((chb >> 3) ^ (node & 7)) << 4) + (chb & 7) * 2;
      *(uint2*)((char*)Tt2 + byte) = make_uint2(lo, hi);
    }
  }
  __syncthreads();
  for (int it = 0; it < 8; ++it) {
    int id = it * 256 + t;                 // [64 node][32 chunk16B]
    int node = id >> 5, c = id & 31;
    uint4 v = *(const uint4*)((char*)Tt2 + node * 512 + ((c ^ (node & 7)) << 4));
    *(uint4*)(inp + ((size_t)b * 64 + node) * 512 + co * 256 + c * 8) = v;
  }
}

// ---------------------------------------------------------------- K4: fused gate GEMM + GRU (32x32x16)
// v11 = round-9 engine (verified 73.5us) widened to 128 ROWS per block (2 m-subtiles):
//   grid (256,4); acc[4][2] = 128 VGPR; Xs 16KB (128 rows x 64K), Ws 24KB -> 40KB, 2 blk/CU.
//   Mechanism: W-staging amortized over 2x compute. Round-9 totals: 590MB W-staging traffic
//   for a 1.44MB weight matrix vs 197MB X; stage-per-MFMA drops 2.67 -> 1.67 KB. Sync
//   structure untouched (single-buffered stage->sync->compute->sync; all pipelining variants
//   regressed in rounds 2/10). Rows+64 reuse the same XOR swizzle (64 = 0 mod 8). Epilogue
//   in two fully-unrolled 64-row chunks (static acc indexing per rule #20); Hh 8KB + F 16KB
//   fit existing LDS. Spill canary: WRITE_SIZE must stay 32768 KB.
// acc[g][mh]: g0=i_r+h_r, g1=i_i+h_i, g2=i_n (kt 0..7), g3=h_n (kt 8..11); mh = row-half.
__global__ __launch_bounds__(256, 2) void k_gates(const u16* __restrict__ inp,
                                                  const u16* __restrict__ h,
                                                  const u16* __restrict__ wcat,
                                                  const float* __restrict__ b_ih,
                                                  const float* __restrict__ b_hh,
                                                  float* __restrict__ out) {
  __shared__ __align__(16) u16 Xs[128 * 64];         // 16 KB: X tile [128 rows][64 K]
  __shared__ __align__(16) u16 Ws[3 * 64 * 64];      // 24 KB: 3 slabs x [64 rows][64 K]
  const u16* wih_b = wcat + 131072;   // [768,512]
  const u16* whh_b = wcat + 524288;   // [768,256]
  int m0 = blockIdx.x * 128;
  int j0 = blockIdx.y * 64;           // 0..3 -> cols j0..j0+63
  int t = threadIdx.x, w = t >> 6, lane = t & 63;
  int wm = w >> 1, wn = w & 1;        // wm: row quarter base (32), wn: col strip (32)
  int rsub8 = lane >> 3, kofs8 = ((lane & 7) ^ rsub8) << 3;
  f32x16 acc[4][2];
#pragma unroll
  for (int g = 0; g < 4; ++g)
#pragma unroll
    for (int mh = 0; mh < 2; ++mh) acc[g][mh] = (f32x16)0.0f;

#pragma unroll 1
  for (int kt = 0; kt < 12; ++kt) {
    bool lo = (kt < 8);
    int k0 = lo ? kt * 64 : (kt - 8) * 64;
    const u16* wb = lo ? wih_b : whh_b;
    int wp = lo ? 512 : 256;
    const u16* xb = lo ? (inp + (size_t)m0 * 512 + kt * 64)
                       : (h   + (size_t)m0 * 256 + (kt - 8) * 64);
    int xp = lo ? 512 : 256;
    // stage: 16 X calls (4/thread, 128 rows) + 24 W calls (6/thread); og wave-uniform
    for (int i = 0; i < 4; ++i) {
      int og = i * 4 + w;                               // 0..15 -> rows og*8..+7
      async16(xb + (size_t)(og * 8 + rsub8) * xp + kofs8, &Xs[og * 8 * 64]);
    }
    for (int i = 0; i < 6; ++i) {
      int og = i * 4 + w;                               // 0..23
      int s = og >> 3, seg = og & 7;
      int jrow = s * 256 + j0 + seg * 8 + rsub8;
      async16(wb + (size_t)jrow * wp + k0 + kofs8, &Ws[s * 4096 + seg * 8 * 64]);
    }
    __syncthreads();
    int rA = 32 * wm + (lane & 31);   // rows 0..63; +64 for second m-subtile
    int rB = 32 * wn + (lane & 31);
    for (int ks = 0; ks < 4; ++ks) {
      int c = ks * 2 + (lane >> 5);
      int sw = (c ^ (rA & 7)) << 3;   // same for rA+64 (64 = 0 mod 8)
      bf16x8 af0 = *(const bf16x8*)(Xs + rA * 64 + sw);
      bf16x8 af1 = *(const bf16x8*)(Xs + (rA + 64) * 64 + sw);
      int aB = rB * 64 + ((c ^ (rB & 7)) << 3);
      bf16x8 b0 = *(const bf16x8*)(Ws + aB);
      bf16x8 b1 = *(const bf16x8*)(Ws + 4096 + aB);
      bf16x8 b2 = *(const bf16x8*)(Ws + 8192 + aB);
      acc[0][0] = __builtin_amdgcn_mfma_f32_32x32x16_bf16(af0, b0, acc[0][0], 0, 0, 0);
      acc[0][1] = __builtin_amdgcn_mfma_f32_32x32x16_bf16(af1, b0, acc[0][1], 0, 0, 0);
      acc[1][0] = __builtin_amdgcn_mfma_f32_32x32x16_bf16(af0, b1, acc[1][0], 0, 0, 0);
      acc[1][1] = __builtin_amdgcn_mfma_f32_32x32x16_bf16(af1, b1, acc[1][1], 0, 0, 0);
      if (lo) {
        acc[2][0] = __builtin_amdgcn_mfma_f32_32x32x16_bf16(af0, b2, acc[2][0], 0, 0, 0);
        acc[2][1] = __builtin_amdgcn_mfma_f32_32x32x16_bf16(af1, b2, acc[2][1], 0, 0, 0);
      } else {
        acc[3][0] = __builtin_amdgcn_mfma_f32_32x32x16_bf16(af0, b2, acc[3][0], 0, 0, 0);
        acc[3][1] = __builtin_amdgcn_mfma_f32_32x32x16_bf16(af1, b2, acc[3][1], 0, 0, 0);
      }
    }
    __syncthreads();
  }
  // epilogue: two 64-row chunks, fully unrolled (static acc[g][mh] indexing, rule #20)
  u16* Hh = Xs;                       // 8 KB used
  float* F = (float*)Ws;              // 16 KB used
  int jl = 32 * wn + (lane & 31);
  int j = j0 + jl;
  float brs = b_ih[j] + b_hh[j];
  float bis = b_ih[256 + j] + b_hh[256 + j];
  float bin = b_ih[512 + j];
  float bhn = b_hh[512 + j];
#pragma unroll
  for (int mh = 0; mh < 2; ++mh) {
    int mb = m0 + mh * 64;
    for (int i = 0; i < 2; ++i) {
      int og = i * 4 + w;                               // 0..7 -> rows og*8..+7
      async16(h + (size_t)(mb + og * 8 + rsub8) * 256 + j0 + (lane & 7) * 8,
              &Hh[og * 8 * 64]);
    }
    __syncthreads();
#pragma unroll
    for (int e = 0; e < 16; ++e) {
      int row = (e & 3) + 8 * (e >> 2) + 4 * (lane >> 5);
      int mloc = 32 * wm + row;
      float r  = sigmoidf_(acc[0][mh][e] + brs);
      float ig = sigmoidf_(acc[1][mh][e] + bis);
      float hn = acc[3][mh][e] + bhn;
      float ng = tanhf_(acc[2][mh][e] + bin + r * hn);
      float hv = bf2f(Hh[mloc * 64 + jl]);
      F[mloc * 64 + jl] = ng + ig * (hv - ng);
    }
    __syncthreads();
    for (int it = 0; it < 8; ++it) {
      int id = it * 256 + t;          // [64 m][32 j-pairs]
      int mloc = id >> 5, jp = (id & 31) * 2;
      float2 v = *(const float2*)(F + mloc * 64 + jp);
      *(float2*)(out + (size_t)(mb + mloc) * 256 + j0 + jp) = v;
    }
    __syncthreads();                  // guard Hh/F reuse in next chunk
  }
}

extern "C" void kernel_launch(void* const* d_in, const int* in_sizes, int n_in,
                              void* d_out, int out_size, void* d_ws, size_t ws_size,
                              hipStream_t stream) {
  (void)in_sizes; (void)n_in; (void)out_size; (void)ws_size;
  const int*   inputs = (const int*)d_in[0];
  const float* A      = (const float*)d_in[1];
  const float* emb    = (const float*)d_in[2];
  const float* W_in   = (const float*)d_in[3];
  const float* b_in   = (const float*)d_in[4];
  const float* W_out  = (const float*)d_in[5];
  const float* b_out  = (const float*)d_in[6];
  const float* w_ih   = (const float*)d_in[7];
  const float* b_ih   = (const float*)d_in[8];
  const float* w_hh   = (const float*)d_in[9];
  const float* b_hh   = (const float*)d_in[10];
  const float* b_iah  = (const float*)d_in[11];
  const float* b_oah  = (const float*)d_in[12];
  float* out = (float*)d_out;

  u16* h    = (u16*)d_ws;                 // BN*256 bf16 = 16.8 MB
  u16* HioT = h + (size_t)BN_ * HHH;      // 33.6 MB
  u16* inp  = HioT + (size_t)BN_ * H2_;   // 33.6 MB
  u16* wcat = inp + (size_t)BN_ * H2_;    // 1.44 MB

  k_convert<<<2816, 256, 0, stream>>>(W_in, W_out, w_ih, w_hh, wcat);
  k_gather_norm<<<BN_ / 4, 256, 0, stream>>>(inputs, emb, h);
  k_hio<<<dim3(BN_ / 128, 4), 256, 0, stream>>>(h, wcat, b_in, b_out, HioT);
  k_amul<<<dim3(BB, 2), 256, 0, stream>>>(A, HioT, b_iah, b_oah, inp);
  k_gates<<<dim3(BN_ / 128, 4), 256, 0, stream>>>(inp, h, wcat, b_ih, b_hh, out);
}